// Round 5
// baseline (148.570 us; speedup 1.0000x reference)
//
#include <hip/hip_runtime.h>
#include <stdint.h>

typedef __attribute__((ext_vector_type(4))) int int4v;           // 16B LDS frag (fp4 x32)
typedef __attribute__((ext_vector_type(8))) int int8v;           // MFMA f8f6f4 A/B operand
typedef __attribute__((ext_vector_type(4))) float floatx4;       // MFMA C/D
typedef __attribute__((ext_vector_type(16))) unsigned char uchar16;

#define MDIM 8192
#define KDIM 2048
#define NDIM 2048
#define BM 256
#define BN 128       // per-tile N; each block does a pair -> 256 cols
#define KB 1024      // bytes per packed fp4 row (K/2)
#define BKB 128      // staged bytes per row per k-tile = 256 fp4 k-elements
#define NKT 8        // KB / BKB

// async global->LDS, 16B per lane. LDS dest = wave-uniform base + lane*16.
__device__ __forceinline__ void load16_lds(const void* g, void* l) {
  __builtin_amdgcn_global_load_lds(
      (const __attribute__((address_space(1))) void*)g,
      (__attribute__((address_space(3))) void*)l, 16, 0, 0);
}

// ---- Phase 1 (fused): binarize X -> fp4 [M][K/2]; binarize+transpose W -> fp4 [N][K/2] ----
// fp4 e2m1: +1 = 0x2, -1 = 0xA. Low nibble = even k (A and B packed identically,
// so any within-k permutation cancels in the dot product).
#define XBLK 2048   // M*K / (256*32)
#define WBLK 512    // N*K / (256*32)

__global__ void binarize_fused(const float* __restrict__ X,
                               const float* __restrict__ W,
                               unsigned char* __restrict__ Xb,
                               unsigned char* __restrict__ WbT) {
  const int b = blockIdx.x;
  if (b < XBLK) {
    size_t i = ((size_t)b * 256 + threadIdx.x) * 32;   // element index, 32/thread
    const float4* xp = (const float4*)(X + i);
    uchar16 o;
#pragma unroll
    for (int h = 0; h < 8; ++h) {
      float4 a = xp[h];
      unsigned n0 = (a.x < 0.f) ? 0xAu : 0x2u;
      unsigned n1 = (a.y < 0.f) ? 0xAu : 0x2u;
      unsigned n2 = (a.z < 0.f) ? 0xAu : 0x2u;
      unsigned n3 = (a.w < 0.f) ? 0xAu : 0x2u;
      o[2 * h]     = (unsigned char)(n0 | (n1 << 4));
      o[2 * h + 1] = (unsigned char)(n2 | (n3 << 4));
    }
    *(uchar16*)(Xb + i / 2) = o;
  } else {
    const int bw = b - XBLK;
    const int nb = bw & 31;                       // n-block (64 wide)
    const int kb = bw >> 5;                       // 0..15
    const int nn = threadIdx.x & 63;              // lane -> consecutive n (coalesced reads)
    const int kc = kb * 4 + (threadIdx.x >> 6);   // 32-k chunk id, 0..63
    const float* wp = W + (size_t)(kc * 32) * NDIM + nb * 64 + nn;
    uchar16 o;
#pragma unroll
    for (int j = 0; j < 16; ++j) {
      unsigned lo = (wp[(size_t)(2 * j) * NDIM] < 0.f) ? 0xAu : 0x2u;
      unsigned hi = (wp[(size_t)(2 * j + 1) * NDIM] < 0.f) ? 0xAu : 0x2u;
      o[j] = (unsigned char)(lo | (hi << 4));
    }
    *(uchar16*)(WbT + (size_t)(nb * 64 + nn) * KB + kc * 16) = o;
  }
}

// one k-step: 2 substeps of k=128, wave tile 64x64 (verified fragment math, R4)
__device__ __forceinline__ void kstep(const unsigned char* As_, const unsigned char* Bs_,
                                      floatx4 (&acc)[4][4], int wm, int wn, int r, int q) {
#pragma unroll
  for (int s2 = 0; s2 < 2; ++s2) {
    const int cswz = ((s2 * 4 + q) ^ (r & 7)) * 16;  // swizzled chunk byte offset
    int8v b8[4];
#pragma unroll
    for (int tn = 0; tn < 4; ++tn) {
      int4v bv = *(const int4v*)(Bs_ + (wn * 64 + tn * 16 + r) * BKB + cswz);
      b8[tn] = int8v{bv[0], bv[1], bv[2], bv[3], 0, 0, 0, 0};
    }
#pragma unroll
    for (int tm = 0; tm < 4; ++tm) {
      int4v av = *(const int4v*)(As_ + (wm * 64 + tm * 16 + r) * BKB + cswz);
      int8v a8 = int8v{av[0], av[1], av[2], av[3], 0, 0, 0, 0};
#pragma unroll
      for (int tn = 0; tn < 4; ++tn)
        // cbsz=4 (A fmt fp4 e2m1), blgp=4 (B fmt fp4); scales = E8M0 127 -> 1.0
        acc[tm][tn] = __builtin_amdgcn_mfma_scale_f32_16x16x128_f8f6f4(
            a8, b8[tn], acc[tm][tn], 4, 4, 0, 0x7F7F7F7F, 0, 0x7F7F7F7F);
    }
  }
}

// half epilogue chunk: 16 rows x 32 cols through a 2KB per-wave slab.
// scatter (C/D layout col=lane&15, row=q*4+v) -> RAW fence -> readback float4 ->
// 2 global_store_dwordx4 (128B contiguous per 8 lanes).
__device__ __forceinline__ void half_chunk(float* slab, const floatx4 (&acc)[4][4],
                                           int tm, int tnh, const float* bv,
                                           float* __restrict__ C, int m0, int wm,
                                           int ncolbase, int lane, int r, int q) {
#pragma unroll
  for (int tn2 = 0; tn2 < 2; ++tn2) {
    const int tn = tnh * 2 + tn2;
#pragma unroll
    for (int v = 0; v < 4; ++v)
      slab[(q * 4 + v) * 32 + tn2 * 16 + r] = acc[tm][tn][v] + bv[tn];
  }
  asm volatile("s_waitcnt lgkmcnt(0)" ::: "memory");  // RAW: writes land before readback
  __builtin_amdgcn_sched_barrier(0);
  const int rr = lane >> 3, c4 = lane & 7;
#pragma unroll
  for (int h = 0; h < 2; ++h) {
    const int row = h * 8 + rr;
    floatx4 val = *(const floatx4*)(&slab[row * 32 + c4 * 4]);
    *(floatx4*)(&C[(size_t)(m0 + wm * 64 + tm * 16 + row) * NDIM + ncolbase + c4 * 4]) = val;
  }
}

// ---- Phase 2: MX-fp4 MFMA GEMM, tile-pair software pipeline.
// Each block: tiles (m0, n0) and (m0, n0+128), shared A panel. PASS1 computes
// tile1 (plain sync loop). PASS2 computes tile2 while draining tile1's epilogue
// one half-chunk per k-iteration; stores ride across barriers via counted
// vmcnt(2) (stores issued AFTER the 6 staging loads -> vmcnt(2) retires exactly
// the loads; in-order vmcnt accounting, m135). Only tile2's epilogue is serial.
__global__ __launch_bounds__(512, 2) void gemm_bin_fp4(
    const unsigned char* __restrict__ A,    // Xb  [M][K/2] fp4
    const unsigned char* __restrict__ B,    // WbT [N][K/2] fp4
    const float* __restrict__ bias,         // [N]
    float* __restrict__ C) {                // [M][N] fp32
  __shared__ __align__(16) unsigned char As[BM * BKB];  // 32 KB
  __shared__ __align__(16) unsigned char Bs[BN * BKB];  // 16 KB
  __shared__ __align__(16) float Sl[8 * 512];           // 16 KB: 2KB slab per wave

  const int tid = threadIdx.x;
  const int lane = tid & 63;
  const int wv = tid >> 6;     // wave 0..7
  const int wm = wv >> 1;      // wave row (4 x 64 over BM=256)
  const int wn = wv & 1;       // wave col (2 x 64 over BN=128)
  const int r = lane & 15;     // MFMA m/n index
  const int q = lane >> 4;     // MFMA quad (k-block select)

  const int m0 = blockIdx.x * BM;
  const int n0 = blockIdx.y * 256;   // tile pair base: tile1 @ n0, tile2 @ n0+128

  floatx4 acc1[4][4] = {};
  floatx4 acc2[4][4] = {};

  // staging offsets (slot -> XOR-swizzled global chunk, same row). A: 2048 slots
  // (rows 0..255, verified R3 geometry); B: 1024 slots (rows 0..127, verified R4).
  int srcA[4], srcB[2];
#pragma unroll
  for (int i = 0; i < 4; ++i) {
    const int s = wv * 256 + i * 64 + lane;
    const int row = s >> 3;
    srcA[i] = row * KB + (((s & 7) ^ (row & 7)) * 16);
  }
#pragma unroll
  for (int i = 0; i < 2; ++i) {
    const int s = wv * 128 + i * 64 + lane;
    const int row = s >> 3;
    srcB[i] = row * KB + (((s & 7) ^ (row & 7)) * 16);
  }
  const unsigned char* Ab = A + (size_t)m0 * KB;
  const unsigned char* Bb1 = B + (size_t)n0 * KB;
  const unsigned char* Bb2 = B + (size_t)(n0 + BN) * KB;

  float* slab = Sl + wv * 512;

  // ---- PASS 1: tile (m0, n0) — plain single-buffered loop ----
  for (int t = 0; t < NKT; ++t) {
    const int kb = t * BKB;
#pragma unroll
    for (int i = 0; i < 4; ++i)
      load16_lds(Ab + kb + srcA[i], As + (wv * 256 + i * 64) * 16);
#pragma unroll
    for (int i = 0; i < 2; ++i)
      load16_lds(Bb1 + kb + srcB[i], Bs + (wv * 128 + i * 64) * 16);
    __syncthreads();  // drains vmcnt before reads
    kstep(As, Bs, acc1, wm, wn, r, q);
    __syncthreads();  // reads done before restage
  }

  float bv1[4];
#pragma unroll
  for (int tn = 0; tn < 4; ++tn) bv1[tn] = bias[n0 + wn * 64 + tn * 16 + r];

  // ---- PASS 2: tile (m0, n0+128) with tile1 epilogue interleaved ----
  // prologue: stage k-tile 0
#pragma unroll
  for (int i = 0; i < 4; ++i)
    load16_lds(Ab + srcA[i], As + (wv * 256 + i * 64) * 16);
#pragma unroll
  for (int i = 0; i < 2; ++i)
    load16_lds(Bb2 + srcB[i], Bs + (wv * 128 + i * 64) * 16);

#pragma unroll
  for (int t = 0; t < NKT; ++t) {
    // open: retire this iteration's 6 staging loads; leave <=2 older... actually
    // <=2 younger stores from last iteration's half-chunk in flight.
    if (t == 0) asm volatile("s_waitcnt vmcnt(0)" ::: "memory");
    else        asm volatile("s_waitcnt vmcnt(2)" ::: "memory");
    __builtin_amdgcn_s_barrier();
    __builtin_amdgcn_sched_barrier(0);
    kstep(As, Bs, acc2, wm, wn, r, q);
    asm volatile("s_waitcnt lgkmcnt(0)" ::: "memory");  // LDS reads done
    __builtin_amdgcn_s_barrier();                       // close: safe to restage
    __builtin_amdgcn_sched_barrier(0);
    if (t < NKT - 1) {
      const int kb = (t + 1) * BKB;
#pragma unroll
      for (int i = 0; i < 4; ++i)
        load16_lds(Ab + kb + srcA[i], As + (wv * 256 + i * 64) * 16);
#pragma unroll
      for (int i = 0; i < 2; ++i)
        load16_lds(Bb2 + kb + srcB[i], Bs + (wv * 128 + i * 64) * 16);
    }
    // tile1 epilogue half-chunk (2 stores, issued AFTER the loads -> vmcnt(2))
    half_chunk(slab, acc1, t >> 1, t & 1, bv1, C, m0, wm,
               n0 + wn * 64 + (t & 1) * 32, lane, r, q);
  }

  // ---- tile2 epilogue (serial) ----
  float bv2[4];
#pragma unroll
  for (int tn = 0; tn < 4; ++tn) bv2[tn] = bias[n0 + BN + wn * 64 + tn * 16 + r];
#pragma unroll
  for (int tm = 0; tm < 4; ++tm)
#pragma unroll
    for (int tnh = 0; tnh < 2; ++tnh) {
      half_chunk(slab, acc2, tm, tnh, bv2, C, m0, wm,
                 n0 + BN + wn * 64 + tnh * 32, lane, r, q);
      // WAR: readback retired before next scatter overwrites slab
      asm volatile("s_waitcnt lgkmcnt(0)" ::: "memory");
      __builtin_amdgcn_sched_barrier(0);
    }
}

extern "C" void kernel_launch(void* const* d_in, const int* in_sizes, int n_in,
                              void* d_out, int out_size, void* d_ws, size_t ws_size,
                              hipStream_t stream) {
  const float* X = (const float*)d_in[0];     // [8192, 2048]
  const float* W = (const float*)d_in[1];     // [2048, 2048]
  const float* bias = (const float*)d_in[2];  // [2048]
  float* out = (float*)d_out;

  unsigned char* Xb = (unsigned char*)d_ws;                 // 8 MB (fp4 packed)
  unsigned char* WbT = Xb + (size_t)MDIM * KDIM / 2;        // 2 MB (ws 10 MB)

  binarize_fused<<<dim3(XBLK + WBLK), 256, 0, stream>>>(X, W, Xb, WbT);
  gemm_bin_fp4<<<dim3(MDIM / BM, NDIM / 256), 512, 0, stream>>>(Xb, WbT, bias, out);
}

// Round 6
// 143.260 us; speedup vs baseline: 1.0371x; 1.0371x over previous
//
#include <hip/hip_runtime.h>
#include <stdint.h>

typedef __attribute__((ext_vector_type(4))) int int4v;           // 16B LDS frag (fp4 x32)
typedef __attribute__((ext_vector_type(8))) int int8v;           // MFMA f8f6f4 A/B operand
typedef __attribute__((ext_vector_type(4))) float floatx4;       // MFMA C/D
typedef __attribute__((ext_vector_type(16))) unsigned char uchar16;

#define MDIM 8192
#define KDIM 2048
#define NDIM 2048
#define BM 256
#define BN 256
#define KB 1024      // bytes per packed fp4 row (K/2)
#define BKB 128      // staged bytes per row per tile = 256 fp4 k-elements
#define NT 8         // KB / BKB

// async global->LDS, 16B per lane. LDS dest = wave-uniform base + lane*16.
__device__ __forceinline__ void load16_lds(const void* g, void* l) {
  __builtin_amdgcn_global_load_lds(
      (const __attribute__((address_space(1))) void*)g,
      (__attribute__((address_space(3))) void*)l, 16, 0, 0);
}

// ---- Phase 1 (fused): binarize X -> fp4 [M][K/2]; binarize+transpose W -> fp4 [N][K/2] ----
// fp4 e2m1: +1 = 0x2, -1 = 0xA. Low nibble = even k (A and B packed identically,
// so any within-k permutation cancels in the dot product).
#define XBLK 2048   // M*K / (256*32)
#define WBLK 512    // N*K / (256*32)

__global__ void binarize_fused(const float* __restrict__ X,
                               const float* __restrict__ W,
                               unsigned char* __restrict__ Xb,
                               unsigned char* __restrict__ WbT) {
  const int b = blockIdx.x;
  if (b < XBLK) {
    size_t i = ((size_t)b * 256 + threadIdx.x) * 32;   // element index, 32/thread
    const float4* xp = (const float4*)(X + i);
    uchar16 o;
#pragma unroll
    for (int h = 0; h < 8; ++h) {
      float4 a = xp[h];
      unsigned n0 = (a.x < 0.f) ? 0xAu : 0x2u;
      unsigned n1 = (a.y < 0.f) ? 0xAu : 0x2u;
      unsigned n2 = (a.z < 0.f) ? 0xAu : 0x2u;
      unsigned n3 = (a.w < 0.f) ? 0xAu : 0x2u;
      o[2 * h]     = (unsigned char)(n0 | (n1 << 4));
      o[2 * h + 1] = (unsigned char)(n2 | (n3 << 4));
    }
    *(uchar16*)(Xb + i / 2) = o;
  } else {
    const int bw = b - XBLK;
    const int nb = bw & 31;                       // n-block (64 wide)
    const int kb = bw >> 5;                       // 0..15
    const int nn = threadIdx.x & 63;              // lane -> consecutive n (coalesced reads)
    const int kc = kb * 4 + (threadIdx.x >> 6);   // 32-k chunk id, 0..63
    const float* wp = W + (size_t)(kc * 32) * NDIM + nb * 64 + nn;
    uchar16 o;
#pragma unroll
    for (int j = 0; j < 16; ++j) {
      unsigned lo = (wp[(size_t)(2 * j) * NDIM] < 0.f) ? 0xAu : 0x2u;
      unsigned hi = (wp[(size_t)(2 * j + 1) * NDIM] < 0.f) ? 0xAu : 0x2u;
      o[j] = (unsigned char)(lo | (hi << 4));
    }
    *(uchar16*)(WbT + (size_t)(nb * 64 + nn) * KB + kc * 16) = o;
  }
}

// ---- Phase 2: MX-fp4 MFMA GEMM, 256x256 tile, 8 waves (wave tile 128x64),
// double-buffered LDS. NEW vs R3: 4-phase k-loop (m196-m201 pattern) — each
// phase {ds_read burst | issue 2 prefetch loads | lgkmcnt+schedbar | setprio(1)
// 16 MFMA setprio(0) | s_barrier}. Next-tile loads spread across phases, waited
// only at next tile's top vmcnt(0) (exactly 8 outstanding there — counted
// semantics, no drain of younger ops). Epilogue slab stride 64->68 floats kills
// the measured 4-way scatter bank conflict. absmax-exact as before.
__global__ __launch_bounds__(512, 2) void gemm_bin_fp4(
    const unsigned char* __restrict__ A,    // Xb  [M][K/2] fp4
    const unsigned char* __restrict__ B,    // WbT [N][K/2] fp4
    const float* __restrict__ bias,         // [N]
    float* __restrict__ C) {                // [M][N] fp32
  __shared__ __align__(16) unsigned char As[2][BM * BKB];  // 2 x 32 KB
  __shared__ __align__(16) unsigned char Bs[2][BN * BKB];  // 2 x 32 KB

  const int tid = threadIdx.x;
  const int lane = tid & 63;
  const int wv = tid >> 6;     // wave 0..7
  const int wm = wv >> 2;      // wave row half (128 rows)
  const int wn = wv & 3;       // wave col quarter (64 cols)
  const int r = lane & 15;     // MFMA m/n index
  const int q = lane >> 4;     // MFMA quad (k-block select)

  const int m0 = blockIdx.x * BM;
  const int n0 = blockIdx.y * BN;

  floatx4 acc[8][4] = {};

  // staging: 2048 16B-chunks per 32KB tile, 256 per wave (4 rounds of 64 lanes)
  const int qbase = wv * 256;
  int srcoff[4];
#pragma unroll
  for (int i = 0; i < 4; ++i) {
    const int s = qbase + i * 64 + lane;
    const int row = s >> 3;
    const int cg = (s & 7) ^ (row & 7);   // global 16B chunk for this (linear) LDS slot
    srcoff[i] = row * KB + cg * 16;       // bytes
  }
  const unsigned char* Ab = A + (size_t)m0 * KB;
  const unsigned char* Bb = B + (size_t)n0 * KB;

  // prologue: stage tile 0 into buffer 0 (8 loads/thread outstanding)
#pragma unroll
  for (int i = 0; i < 4; ++i) {
    load16_lds(Ab + srcoff[i], &As[0][(qbase + i * 64) * 16]);
    load16_lds(Bb + srcoff[i], &Bs[0][(qbase + i * 64) * 16]);
  }

  for (int t = 0; t < NT; ++t) {
    const int cur = t & 1;
    const int kbb = (t + 1) * BKB;
    const bool pf = (t < NT - 1);

    // tile top: the 8 loads for THIS tile (issued during t-1's phases, or the
    // prologue) are the only outstanding VMEM ops -> vmcnt(0) is a counted wait.
    asm volatile("s_waitcnt vmcnt(0)" ::: "memory");
    __builtin_amdgcn_s_barrier();

    int8v b8[4], a8[4];
    const int cs0 = (q ^ (r & 7)) * 16;          // s2=0 swizzled chunk offset
    const int cs1 = ((4 + q) ^ (r & 7)) * 16;    // s2=1

    // ---- P0: s2=0, tm 0..3 ----
#pragma unroll
    for (int tn = 0; tn < 4; ++tn) {
      int4v v = *(const int4v*)(&Bs[cur][(wn * 64 + tn * 16 + r) * BKB + cs0]);
      b8[tn] = int8v{v[0], v[1], v[2], v[3], 0, 0, 0, 0};
    }
#pragma unroll
    for (int tm = 0; tm < 4; ++tm) {
      int4v v = *(const int4v*)(&As[cur][(wm * 128 + tm * 16 + r) * BKB + cs0]);
      a8[tm] = int8v{v[0], v[1], v[2], v[3], 0, 0, 0, 0};
    }
    if (pf) {
      load16_lds(Ab + kbb + srcoff[0], &As[cur ^ 1][(qbase + 0 * 64) * 16]);
      load16_lds(Ab + kbb + srcoff[1], &As[cur ^ 1][(qbase + 1 * 64) * 16]);
    }
    asm volatile("s_waitcnt lgkmcnt(0)" ::: "memory");
    __builtin_amdgcn_sched_barrier(0);
    __builtin_amdgcn_s_setprio(1);
#pragma unroll
    for (int tm = 0; tm < 4; ++tm)
#pragma unroll
      for (int tn = 0; tn < 4; ++tn)
        acc[tm][tn] = __builtin_amdgcn_mfma_scale_f32_16x16x128_f8f6f4(
            a8[tm], b8[tn], acc[tm][tn], 4, 4, 0, 0x7F7F7F7F, 0, 0x7F7F7F7F);
    __builtin_amdgcn_s_setprio(0);
    __builtin_amdgcn_s_barrier();

    // ---- P1: s2=0, tm 4..7 (b8 reused) ----
#pragma unroll
    for (int tm = 0; tm < 4; ++tm) {
      int4v v = *(const int4v*)(&As[cur][(wm * 128 + (tm + 4) * 16 + r) * BKB + cs0]);
      a8[tm] = int8v{v[0], v[1], v[2], v[3], 0, 0, 0, 0};
    }
    if (pf) {
      load16_lds(Ab + kbb + srcoff[2], &As[cur ^ 1][(qbase + 2 * 64) * 16]);
      load16_lds(Ab + kbb + srcoff[3], &As[cur ^ 1][(qbase + 3 * 64) * 16]);
    }
    asm volatile("s_waitcnt lgkmcnt(0)" ::: "memory");
    __builtin_amdgcn_sched_barrier(0);
    __builtin_amdgcn_s_setprio(1);
#pragma unroll
    for (int tm = 0; tm < 4; ++tm)
#pragma unroll
      for (int tn = 0; tn < 4; ++tn)
        acc[tm + 4][tn] = __builtin_amdgcn_mfma_scale_f32_16x16x128_f8f6f4(
            a8[tm], b8[tn], acc[tm + 4][tn], 4, 4, 0, 0x7F7F7F7F, 0, 0x7F7F7F7F);
    __builtin_amdgcn_s_setprio(0);
    __builtin_amdgcn_s_barrier();

    // ---- P2: s2=1, tm 0..3 ----
#pragma unroll
    for (int tn = 0; tn < 4; ++tn) {
      int4v v = *(const int4v*)(&Bs[cur][(wn * 64 + tn * 16 + r) * BKB + cs1]);
      b8[tn] = int8v{v[0], v[1], v[2], v[3], 0, 0, 0, 0};
    }
#pragma unroll
    for (int tm = 0; tm < 4; ++tm) {
      int4v v = *(const int4v*)(&As[cur][(wm * 128 + tm * 16 + r) * BKB + cs1]);
      a8[tm] = int8v{v[0], v[1], v[2], v[3], 0, 0, 0, 0};
    }
    if (pf) {
      load16_lds(Bb + kbb + srcoff[0], &Bs[cur ^ 1][(qbase + 0 * 64) * 16]);
      load16_lds(Bb + kbb + srcoff[1], &Bs[cur ^ 1][(qbase + 1 * 64) * 16]);
    }
    asm volatile("s_waitcnt lgkmcnt(0)" ::: "memory");
    __builtin_amdgcn_sched_barrier(0);
    __builtin_amdgcn_s_setprio(1);
#pragma unroll
    for (int tm = 0; tm < 4; ++tm)
#pragma unroll
      for (int tn = 0; tn < 4; ++tn)
        acc[tm][tn] = __builtin_amdgcn_mfma_scale_f32_16x16x128_f8f6f4(
            a8[tm], b8[tn], acc[tm][tn], 4, 4, 0, 0x7F7F7F7F, 0, 0x7F7F7F7F);
    __builtin_amdgcn_s_setprio(0);
    __builtin_amdgcn_s_barrier();

    // ---- P3: s2=1, tm 4..7 (no closing barrier; next tile's top syncs) ----
#pragma unroll
    for (int tm = 0; tm < 4; ++tm) {
      int4v v = *(const int4v*)(&As[cur][(wm * 128 + (tm + 4) * 16 + r) * BKB + cs1]);
      a8[tm] = int8v{v[0], v[1], v[2], v[3], 0, 0, 0, 0};
    }
    if (pf) {
      load16_lds(Bb + kbb + srcoff[2], &Bs[cur ^ 1][(qbase + 2 * 64) * 16]);
      load16_lds(Bb + kbb + srcoff[3], &Bs[cur ^ 1][(qbase + 3 * 64) * 16]);
    }
    asm volatile("s_waitcnt lgkmcnt(0)" ::: "memory");
    __builtin_amdgcn_sched_barrier(0);
    __builtin_amdgcn_s_setprio(1);
#pragma unroll
    for (int tm = 0; tm < 4; ++tm)
#pragma unroll
      for (int tn = 0; tn < 4; ++tn)
        acc[tm + 4][tn] = __builtin_amdgcn_mfma_scale_f32_16x16x128_f8f6f4(
            a8[tm], b8[tn], acc[tm + 4][tn], 4, 4, 0, 0x7F7F7F7F, 0, 0x7F7F7F7F);
    __builtin_amdgcn_s_setprio(0);
  }

  // ---- epilogue: vectorized C-write via per-wave LDS transpose slab ----
  // MFMA C/D layout: col=lane&15, row=q*4+v. Slab row stride 68 floats (272B,
  // 16B-aligned): scatter bank = (16q+4v+16tn+r)%32 -> q-pairs alias = 2-way
  // (free, m136); readback b128 stays contiguous-conflict-free.
  __syncthreads();  // all waves done with MFMA LDS reads; safe to reuse As
  float* slab = (float*)(&As[0][0]) + wv * 1088;   // 16*68 floats = 4352B/wave

  float bv[4];
#pragma unroll
  for (int tn = 0; tn < 4; ++tn) bv[tn] = bias[n0 + wn * 64 + tn * 16 + r];

  const int lrow = lane >> 4;   // 0..3  (row within 4-row store group)
  const int lc4 = lane & 15;    // float4 column 0..15 (16 lanes = 256B contiguous)

#pragma unroll
  for (int tm = 0; tm < 8; ++tm) {
    // scatter fragment group (bias added) into slab — wave-private
#pragma unroll
    for (int tn = 0; tn < 4; ++tn)
#pragma unroll
      for (int v = 0; v < 4; ++v)
        slab[(q * 4 + v) * 68 + tn * 16 + r] = acc[tm][tn][v] + bv[tn];
    // RAW fence: slab writes must land before the transpose readback
    asm volatile("s_waitcnt lgkmcnt(0)" ::: "memory");
    __builtin_amdgcn_sched_barrier(0);
    // read back row-major as float4, store 4 rows x 256B contiguous per instr
#pragma unroll
    for (int j = 0; j < 4; ++j) {
      const int row = j * 4 + lrow;
      floatx4 val = *(const floatx4*)(&slab[row * 68 + lc4 * 4]);
      *(floatx4*)(&C[(size_t)(m0 + wm * 128 + tm * 16 + row) * NDIM +
                     n0 + wn * 64 + lc4 * 4]) = val;
    }
    // WAR fence: readback must retire before next iteration overwrites slab
    asm volatile("s_waitcnt lgkmcnt(0)" ::: "memory");
    __builtin_amdgcn_sched_barrier(0);
  }
}

extern "C" void kernel_launch(void* const* d_in, const int* in_sizes, int n_in,
                              void* d_out, int out_size, void* d_ws, size_t ws_size,
                              hipStream_t stream) {
  const float* X = (const float*)d_in[0];     // [8192, 2048]
  const float* W = (const float*)d_in[1];     // [2048, 2048]
  const float* bias = (const float*)d_in[2];  // [2048]
  float* out = (float*)d_out;

  unsigned char* Xb = (unsigned char*)d_ws;                 // 8 MB (fp4 packed)
  unsigned char* WbT = Xb + (size_t)MDIM * KDIM / 2;        // 2 MB (ws 10 MB)

  binarize_fused<<<dim3(XBLK + WBLK), 256, 0, stream>>>(X, W, Xb, WbT);
  gemm_bin_fp4<<<dim3(MDIM / BM, NDIM / BN), 512, 0, stream>>>(Xb, WbT, bias, out);
}